// Round 5
// baseline (95.488 us; speedup 1.0000x reference)
//
#include <hip/hip_runtime.h>

// NestedFormula: DEPTH=4, V=4, B=131072. n1=125, n2=25, n3=5, n4=1.
//
// 4-way tree split per batch element, all INSIDE one block:
//   block = 4 waves x 64 lanes; wave r handles split r of elements
//   b = blockIdx.x*64 + lane. r is wave-uniform -> no divergence, params
//   stay on the scalar pipe. LDS reduction (1KB) replaces the R4 global
//   atomics + memset dispatch.
// Split r: A_r = lam4[r]*x_r^pow4[r] * f3(r)            (125 exps)
//        + B_r = lam3[4,r]*x_r^pow3[4,r] * f2(20+r)     ( 25 exps)
//        + C_r = lam2[24,r]*x_r^pow2[24,r] * f1(120+r)  (  5 exps)
//        + (r==0 ? f1(124) : 0)                         (  4 exps)
// Body ~6KB: fits the 32KB I$ (R3's 128KB unrolled body streamed from L2
// at ~26 cyc/inst — the real cause of its 88us).
// __launch_bounds__(256,8): pin VGPR<=64 so 8 blocks/CU = 8 waves/SIMD.

#define VV 4

__device__ __forceinline__ float f1_eval(int n1, const float lx[VV],
    const float* __restrict__ lam0, const float* __restrict__ lam1,
    const float* __restrict__ pow1)
{
    float f = lam0[n1];
#pragma unroll
    for (int v = 0; v < VV; ++v)
        f = fmaf(lam1[n1 * VV + v],
                 __builtin_amdgcn_exp2f(pow1[n1 * VV + v] * lx[v]), f);
    return f;
}

__device__ __forceinline__ float f2_eval(int n2, const float lx[VV],
    const float* __restrict__ lam0, const float* __restrict__ lam1,
    const float* __restrict__ pow1, const float* __restrict__ lam2,
    const float* __restrict__ pow2)
{
    float acc = 0.f;
#pragma unroll
    for (int c1 = 0; c1 < VV; ++c1) {
        float f1 = f1_eval(n2 * (VV + 1) + c1, lx, lam0, lam1, pow1);
        acc = fmaf(lam2[n2 * VV + c1] *
                       __builtin_amdgcn_exp2f(pow2[n2 * VV + c1] * lx[c1]),
                   f1, acc);
    }
    return acc + f1_eval(n2 * (VV + 1) + VV, lx, lam0, lam1, pow1);
}

__device__ __forceinline__ float f3_eval(int n3, const float lx[VV],
    const float* __restrict__ lam0, const float* __restrict__ lam1,
    const float* __restrict__ pow1, const float* __restrict__ lam2,
    const float* __restrict__ pow2, const float* __restrict__ lam3,
    const float* __restrict__ pow3)
{
    float acc = 0.f;
#pragma unroll
    for (int c2 = 0; c2 < VV; ++c2) {
        float f2 = f2_eval(n3 * (VV + 1) + c2, lx, lam0, lam1, pow1, lam2, pow2);
        acc = fmaf(lam3[n3 * VV + c2] *
                       __builtin_amdgcn_exp2f(pow3[n3 * VV + c2] * lx[c2]),
                   f2, acc);
    }
    return acc + f2_eval(n3 * (VV + 1) + VV, lx, lam0, lam1, pow1, lam2, pow2);
}

__global__ __launch_bounds__(256, 8) void nested_formula_lds(
    const float4* __restrict__ x,      // (B, 4)
    const float*  __restrict__ lam0,   // (125,)
    const float*  __restrict__ lam1,   // (125,4)
    const float*  __restrict__ pow1,   // (125,4)
    const float*  __restrict__ lam2,   // (25,4)
    const float*  __restrict__ pow2,   // (25,4)
    const float*  __restrict__ lam3,   // (5,4)
    const float*  __restrict__ pow3,   // (5,4)
    const float*  __restrict__ lam4,   // (1,4)
    const float*  __restrict__ pow4,   // (1,4)
    float* __restrict__ out,           // (B,)
    int B)
{
    const int lane = threadIdx.x & 63;
    const int r    = threadIdx.x >> 6;          // wave id 0..3, wave-uniform
    const int b    = blockIdx.x * 64 + lane;    // batch element

    __shared__ float red[4][64];                // 1KB; 2-way bank alias = free

    float partial = 0.f;
    if (b < B) {
        float4 xv = x[b];
        float lx[VV] = { __builtin_amdgcn_logf(xv.x), __builtin_amdgcn_logf(xv.y),
                         __builtin_amdgcn_logf(xv.z), __builtin_amdgcn_logf(xv.w) };
        const float lxr = (r == 0) ? lx[0] : (r == 1) ? lx[1]
                        : (r == 2) ? lx[2] : lx[3];

        // A_r: depth-3 subtree r, weighted by the depth-4 edge
        float f3 = f3_eval(r, lx, lam0, lam1, pow1, lam2, pow2, lam3, pow3);
        partial = lam4[r] * __builtin_amdgcn_exp2f(pow4[r] * lxr) * f3;

        // B_r: depth-2 node (20+r) = child r of depth-3 node 4
        float f2 = f2_eval(4 * (VV + 1) + r, lx, lam0, lam1, pow1, lam2, pow2);
        partial = fmaf(lam3[4 * VV + r] *
                           __builtin_amdgcn_exp2f(pow3[4 * VV + r] * lxr),
                       f2, partial);

        // C_r: depth-1 node (120+r) = child r of depth-2 node 24
        float f1 = f1_eval(24 * (VV + 1) + r, lx, lam0, lam1, pow1);
        partial = fmaf(lam2[24 * VV + r] *
                           __builtin_amdgcn_exp2f(pow2[24 * VV + r] * lxr),
                       f1, partial);

        // last chain: f1(124) contributes raw; assign to wave 0 (uniform branch)
        if (r == 0)
            partial += f1_eval(24 * (VV + 1) + VV, lx, lam0, lam1, pow1);
    }

    red[r][lane] = partial;
    __syncthreads();

    if (r == 0 && b < B)
        out[b] = (red[0][lane] + red[1][lane]) + (red[2][lane] + red[3][lane]);
}

extern "C" void kernel_launch(void* const* d_in, const int* in_sizes, int n_in,
                              void* d_out, int out_size, void* d_ws, size_t ws_size,
                              hipStream_t stream) {
    const float4* x    = (const float4*)d_in[0];
    const float*  lam0 = (const float*)d_in[1];
    const float*  lam1 = (const float*)d_in[2];
    const float*  pow1 = (const float*)d_in[3];
    const float*  lam2 = (const float*)d_in[4];
    const float*  pow2 = (const float*)d_in[5];
    const float*  lam3 = (const float*)d_in[6];
    const float*  pow3 = (const float*)d_in[7];
    const float*  lam4 = (const float*)d_in[8];
    const float*  pow4 = (const float*)d_in[9];
    float* out = (float*)d_out;

    int B = in_sizes[0] / 4;  // x is (B, 4)
    dim3 block(256, 1, 1);
    dim3 grid((B + 63) / 64, 1, 1);   // 2048 blocks, 4 waves each
    nested_formula_lds<<<grid, block, 0, stream>>>(
        x, lam0, lam1, pow1, lam2, pow2, lam3, pow3, lam4, pow4, out, B);
}